// Round 14
// baseline (189.457 us; speedup 1.0000x reference)
//
#include <hip/hip_runtime.h>
#include <stdint.h>

typedef _Float16 f16;
typedef _Float16 f16x8 __attribute__((ext_vector_type(8)));
typedef float    f32x4 __attribute__((ext_vector_type(4)));
typedef unsigned int u32x4 __attribute__((ext_vector_type(4)));
typedef unsigned int u32x2 __attribute__((ext_vector_type(2)));
typedef unsigned short u16;

#define MFMA16(A,B,C) __builtin_amdgcn_mfma_f32_16x16x32_f16(A,B,C,0,0,0)

__device__ __forceinline__ void gload_lds16(const void* g, void* l) {
  auto gp = reinterpret_cast<const __attribute__((address_space(1))) unsigned int*>(
      reinterpret_cast<uintptr_t>(g));
  auto lp = reinterpret_cast<__attribute__((address_space(3))) unsigned int*>(
      reinterpret_cast<uintptr_t>(l));
  __builtin_amdgcn_global_load_lds(gp, lp, 16, 0, 0);
}

// round-to-nearest fp16 pack (precision-relevant conversions)
__device__ __forceinline__ unsigned pk16(float a, float b) {
  unsigned short ua = __builtin_bit_cast(unsigned short, (f16)a);
  unsigned short ub = __builtin_bit_cast(unsigned short, (f16)b);
  return ((unsigned)ub << 16) | (unsigned)ua;
}
// single-instruction RTZ pack (P values in attn hot path)
__device__ __forceinline__ unsigned pk2rtz(float a, float b) {
  return __builtin_bit_cast(unsigned, __builtin_amdgcn_cvt_pkrtz(a, b));
}
// 2^x via v_exp_f32
__device__ __forceinline__ float ex2(float x) {
  float r; asm("v_exp_f32 %0, %1" : "=v"(r) : "v"(x)); return r;
}
__device__ __forceinline__ f16x8 asf16(u32x4 v) { return __builtin_bit_cast(f16x8, v); }

#define LOG2E 1.44269504088896f

// ---------------- prep: fp32->fp16 convert (blocks 0..4095) + weight
// transpose/convert (blocks 4096..5119) in ONE launch (verified round 4) ------
__global__ __launch_bounds__(256) void k_prep(const float* __restrict__ x, u16* __restrict__ xb,
                                              const float* __restrict__ Wq, const float* __restrict__ Wk,
                                              const float* __restrict__ Wv, const float* __restrict__ Wo,
                                              u16* __restrict__ WTq, u16* __restrict__ WTk,
                                              u16* __restrict__ WTv, u16* __restrict__ WTo) {
  __shared__ float tile[64][65];
  int tid = threadIdx.x;
  if (blockIdx.x < 4096) {
    int i = blockIdx.x * 256 + tid;          // i < 1048576 exactly
    const float4* p = (const float4*)x + (size_t)i * 2;
    float4 a = p[0], b = p[1];
    u32x4 o = { pk16(a.x, a.y), pk16(a.z, a.w), pk16(b.x, b.y), pk16(b.z, b.w) };
    *((u32x4*)xb + i) = o;
    return;
  }
  int bid = blockIdx.x - 4096;               // [0,1024)
  int z = bid >> 8;
  const float* W = (z == 0) ? Wq : (z == 1) ? Wk : (z == 2) ? Wv : Wo;
  u16* WT = (z == 0) ? WTq : (z == 1) ? WTk : (z == 2) ? WTv : WTo;
  int r0 = ((bid >> 4) & 15) * 64, c0 = (bid & 15) * 64;
#pragma unroll
  for (int i = 0; i < 4; ++i) {
    int idx = tid + i * 256;
    int row = idx >> 4, ch = (idx & 15) * 4;
    float4 v = *(const float4*)&W[(size_t)(r0 + row) * 1024 + c0 + ch];
    tile[row][ch + 0] = v.x; tile[row][ch + 1] = v.y;
    tile[row][ch + 2] = v.z; tile[row][ch + 3] = v.w;
  }
  __syncthreads();
#pragma unroll
  for (int i = 0; i < 4; ++i) {
    int idx = tid + i * 256;
    int orow = idx >> 4, ch = (idx & 15) * 4;
    u32x2 o = { pk16(tile[ch + 0][orow], tile[ch + 1][orow]),
                pk16(tile[ch + 2][orow], tile[ch + 3][orow]) };
    *(u32x2*)&WT[(size_t)(c0 + orow) * 1024 + r0 + ch] = o;
  }
}

// ---------------- shared GEMM mainloop: 3-stage pipeline, counted vmcnt --------
// Round-6-verified: 128x256 tile, 8 waves, 3-buffer rotation, distance-2
// prefetch, ONE counted vmcnt + ONE barrier per K-tile.
// LDS: A [128 rows][32 k] (8KB/buf), B [256 rows][32 k] (16KB/buf), x3 = 72KB.
// 64B rows, 4x16B chunks, chunk swizzle ch^((row>>1)&3).
__device__ __forceinline__ void gemm_core(const u16* __restrict__ A, const u16* __restrict__ B,
                                          u16* sA, u16* sB, int m0, int n0, f32x4 acc[4][4]) {
  const int tid = threadIdx.x;               // [0,512)
  const int lane = tid & 63;
  const int w = tid >> 6;                    // [0,8)
  const int wr = w >> 2, wc = w & 3;         // 2m x 4n wave grid
  const int c = lane & 15, g = lane >> 4;
#pragma unroll
  for (int i = 0; i < 4; ++i)
#pragma unroll
    for (int j = 0; j < 4; ++j) acc[i][j] = (f32x4){0.f, 0.f, 0.f, 0.f};

  auto stage = [&](int buf, int kt) {
    {  // A: 128 rows x 32k = 8KB, 1 load/thread
      int L = tid * 16;
      int row = L >> 6;
      int chl = (L >> 4) & 3;
      int chg = chl ^ ((row >> 1) & 3);      // inverse-swizzled global source
      gload_lds16(A + (size_t)(m0 + row) * 1024 + kt + chg * 8, (char*)sA + buf * 8192 + L);
    }
#pragma unroll
    for (int j = 0; j < 2; ++j) {  // B: 256 rows x 32k = 16KB, 2 loads/thread
      int L = j * 8192 + tid * 16;
      int row = L >> 6;
      int chl = (L >> 4) & 3;
      int chg = chl ^ ((row >> 1) & 3);
      gload_lds16(B + (size_t)(n0 + row) * 1024 + kt + chg * 8, (char*)sB + buf * 16384 + L);
    }
  };

  stage(0, 0);
  stage(1, 32);
  int cur = 0;
  for (int kt = 0; kt < 1024; kt += 32) {
    if (kt < 1024 - 32) {
      asm volatile("s_waitcnt vmcnt(3)" ::: "memory");   // tile t done; t+1 in flight
    } else {
      asm volatile("s_waitcnt vmcnt(0)" ::: "memory");   // tail: drain last tile
    }
    __builtin_amdgcn_s_barrier();
    if (kt + 64 < 1024) {
      int nb = cur + 2; if (nb >= 3) nb -= 3;
      stage(nb, kt + 64);
    }
    const char* cA = (const char*)sA + cur * 8192;
    const char* cB = (const char*)sB + cur * 16384;
    u32x4 av[4], bv[4];
#pragma unroll
    for (int mi = 0; mi < 4; ++mi) {
      int row = wr * 64 + mi * 16 + c;
      av[mi] = *(const u32x4*)(cA + row * 64 + ((g ^ ((row >> 1) & 3)) << 4));
    }
#pragma unroll
    for (int ni = 0; ni < 4; ++ni) {
      int row = wc * 64 + ni * 16 + c;
      bv[ni] = *(const u32x4*)(cB + row * 64 + ((g ^ ((row >> 1) & 3)) << 4));
    }
#pragma unroll
    for (int mi = 0; mi < 4; ++mi)
#pragma unroll
      for (int ni = 0; ni < 4; ++ni)
        acc[mi][ni] = MFMA16(asf16(av[mi]), asf16(bv[ni]), acc[mi][ni]);
    cur = (cur == 2) ? 0 : cur + 1;
  }
}

// ---------------- QKV projection (grid x=m-tile[64], y=nt[12]) ----------------
__global__ __launch_bounds__(512, 4) void k_qkv(const u16* __restrict__ xb,
                                             const u16* __restrict__ wtq, const u16* __restrict__ wtk,
                                             const u16* __restrict__ wtv,
                                             const float* __restrict__ bq, const float* __restrict__ bk,
                                             const float* __restrict__ bv,
                                             u16* __restrict__ Qb, u16* __restrict__ Kb,
                                             u16* __restrict__ VTb) {
  __shared__ alignas(16) u16 sA[3 * 128 * 32];
  __shared__ alignas(16) u16 sB[3 * 256 * 32];
  int m0 = blockIdx.x * 128;
  int nt = blockIdx.y;                       // [0,12)
  int wsel = nt >> 2;
  int n0 = (nt & 3) * 256;
  const u16* WT = (wsel == 0) ? wtq : (wsel == 1) ? wtk : wtv;
  const float* bias = (wsel == 0) ? bq : (wsel == 1) ? bk : bv;
  f32x4 acc[4][4];
  gemm_core(xb, WT, sA, sB, m0, n0, acc);

  const int lane = threadIdx.x & 63;
  const int w = threadIdx.x >> 6;
  const int wr = w >> 2, wc = w & 3, c = lane & 15, g = lane >> 4;
#pragma unroll
  for (int mi = 0; mi < 4; ++mi) {
#pragma unroll
    for (int ni = 0; ni < 4; ++ni) {
      int ncol = n0 + wc * 64 + ni * 16 + c;
      float bcol = bias[ncol];
      int h = ncol >> 6, d = ncol & 63;
#pragma unroll
      for (int e = 0; e < 4; ++e) {
        int m = m0 + wr * 64 + mi * 16 + g * 4 + e;
        int b = m >> 11, t = m & 2047;
        int bh = (b << 4) | h;
        float val = acc[mi][ni][e] + bcol;
        if (wsel == 0) {
          // fold 1/sqrt(d_k) AND log2(e) into Q (softmax runs in exp2 domain)
          Qb[((size_t)bh * 2048 + t) * 64 + d] = __builtin_bit_cast(u16, (f16)(val * (0.125f * LOG2E)));
        } else if (wsel == 1) {
          Kb[((size_t)bh * 2048 + t) * 64 + d] = __builtin_bit_cast(u16, (f16)val);
        } else {
          VTb[((size_t)bh * 64 + d) * 2048 + t] = __builtin_bit_cast(u16, (f16)val);
        }
      }
    }
  }
}

// ---------------- flash attention: 4 waves x 32 q-rows, KVBLK=64, dbuf ----------
// Verified round-3/round-6 kernel, byte-identical (pair-wise permlane16_swap
// network with sigma-permuted V^T chunk staging). THREE restructure attempts
// (R1 compile-time-unrolled buffers, R7 deferred-PV, R13 8-wave co-staging)
// all failed numerically despite provably-equivalent dataflow — this body and
// its compilation context are load-bearing; do not modify.
__global__ __launch_bounds__(256) void k_attn(const u16* __restrict__ Qb, const u16* __restrict__ Kb,
                                              const u16* __restrict__ VTb, u16* __restrict__ Ob) {
  __shared__ alignas(16) u16 Ks[2][64 * 64];
  __shared__ alignas(16) u16 VTs[2][64 * 64];
  const int tid = threadIdx.x, lane = tid & 63, w = tid >> 6;
  const int c = lane & 15, g = lane >> 4;
  // XCD swizzle: lin = bh_local*128 + qblk*8 + xcd  (bijective over [0,1024))
  const int lin = blockIdx.x;
  const int bh = (lin & 7) * 8 + (lin >> 7);
  const int qblk = (lin >> 3) & 15;
  const int qw = qblk * 128 + w * 32;           // wave's 32-row q base
  const size_t kbase = (size_t)bh * 2048 * 64;  // K rows base (elems)
  const size_t vbase = (size_t)bh * 64 * 2048;  // VT rows base

  // Q fragments (B-operand layout): qa[qb*2+0]: row qw+qb*16+c elems g*8..+7;
  //                                 qa[qb*2+1]: same row, elems 32+g*8..+7
  u32x4 qa0 = *(const u32x4*)(Qb + ((size_t)bh * 2048 + qw + c) * 64 + g * 8);
  u32x4 qa1 = *(const u32x4*)(Qb + ((size_t)bh * 2048 + qw + c) * 64 + 32 + g * 8);
  u32x4 qa2 = *(const u32x4*)(Qb + ((size_t)bh * 2048 + qw + 16 + c) * 64 + g * 8);
  u32x4 qa3 = *(const u32x4*)(Qb + ((size_t)bh * 2048 + qw + 16 + c) * 64 + 32 + g * 8);

  const u32x4 ONES = { 0x3C003C00u, 0x3C003C00u, 0x3C003C00u, 0x3C003C00u }; // f16 1.0 x8

  // ---- hoisted staging addresses (per-lane, loop-invariant bases) ----
  const int L0 = tid * 16, L1 = 4096 + tid * 16;
  const int row0 = L0 >> 7, row1 = L1 >> 7;
  const int chg0 = ((L0 >> 4) & 7) ^ (row0 & 7);
  const int chg1 = ((L1 >> 4) & 7) ^ (row1 & 7);
  // VT chunk permutation sigma (swap chunk-index bits 0 and 1)
  const int vchg0 = (chg0 & 4) | ((chg0 & 1) << 1) | ((chg0 >> 1) & 1);
  const int vchg1 = (chg1 & 4) | ((chg1 & 1) << 1) | ((chg1 >> 1) & 1);
  const u16* kg0 = Kb + kbase + (size_t)row0 * 64 + chg0 * 8;
  const u16* kg1 = Kb + kbase + (size_t)row1 * 64 + chg1 * 8;
  const u16* vg0 = VTb + vbase + (size_t)row0 * 2048 + vchg0 * 8;
  const u16* vg1 = VTb + vbase + (size_t)row1 * 2048 + vchg1 * 8;

  auto stage = [&](int buf, int kt) {
    gload_lds16(kg0 + (size_t)kt * 64, (char*)Ks[buf] + L0);
    gload_lds16(kg1 + (size_t)kt * 64, (char*)Ks[buf] + L1);
    gload_lds16(vg0 + kt,              (char*)VTs[buf] + L0);
    gload_lds16(vg1 + kt,              (char*)VTs[buf] + L1);
  };

  // ---- hoisted LDS read offsets (kb/db-invariant swizzle) ----
  const int A0 = c * 128 + ((g ^ (c & 7)) << 4);
  const int A1 = A0 ^ 0x40;                     // (g+4) chunk partner

  f32x4 oa[2][4];
  f32x4 la[2];
#pragma unroll
  for (int qb = 0; qb < 2; ++qb) {
    la[qb] = (f32x4){0.f, 0.f, 0.f, 0.f};
#pragma unroll
    for (int i = 0; i < 4; ++i) oa[qb][i] = (f32x4){0.f, 0.f, 0.f, 0.f};
  }

  stage(0, 0);
  __syncthreads();
  int cur = 0;
  for (int kt = 0; kt < 2048; kt += 64) {
    if (kt + 64 < 2048) stage(cur ^ 1, kt + 64);  // prefetch next K/V tile

    // QK^T (swapped operands) -> exp2 -> packed fp16 P, per q-block
    // wds[qb][kb*2+j] packs P[k=kt+kb*16+g*4+{2j,2j+1}][q=qw+qb*16+c]
    unsigned wds[2][8];
    __builtin_amdgcn_s_setprio(1);
    const char* cK = (const char*)Ks[cur];
#pragma unroll
    for (int kb = 0; kb < 4; ++kb) {
      const char* bp = cK + kb * 2048;
      u32x4 k0 = *(const u32x4*)(bp + A0);
      u32x4 k1 = *(const u32x4*)(bp + A1);
      f32x4 z0 = (f32x4){0.f, 0.f, 0.f, 0.f};
      z0 = MFMA16(asf16(k0), asf16(qa0), z0);
      z0 = MFMA16(asf16(k1), asf16(qa1), z0);
      wds[0][kb * 2]     = pk2rtz(ex2(z0[0]), ex2(z0[1]));
      wds[0][kb * 2 + 1] = pk2rtz(ex2(z0[2]), ex2(z0[3]));
      f32x4 z1 = (f32x4){0.f, 0.f, 0.f, 0.f};
      z1 = MFMA16(asf16(k0), asf16(qa2), z1);
      z1 = MFMA16(asf16(k1), asf16(qa3), z1);
      wds[1][kb * 2]     = pk2rtz(ex2(z1[0]), ex2(z1[1]));
      wds[1][kb * 2 + 1] = pk2rtz(ex2(z1[2]), ex2(z1[3]));
    }
    __builtin_amdgcn_s_setprio(0);

    // redistribute P -> B-fragment layout: pair-wise permlane16_swap only.
    // swap16(w0,w2): m'=[w0.g0,w2.g0,w0.g2,w2.g2] = B-word0, n' = B-word2
    // (valid against the sigma-permuted V^T chunk order staged above).
    u32x4 pb0[2], pb1[2];
#pragma unroll
    for (int qb = 0; qb < 2; ++qb) {
      unsigned m0 = wds[qb][0], n0 = wds[qb][2];
      unsigned m1 = wds[qb][1], n1 = wds[qb][3];
      unsigned m2 = wds[qb][4], n2 = wds[qb][6];
      unsigned m3 = wds[qb][5], n3 = wds[qb][7];
      asm("v_permlane16_swap_b32 %0, %1" : "+v"(m0), "+v"(n0));
      asm("v_permlane16_swap_b32 %0, %1" : "+v"(m1), "+v"(n1));
      asm("v_permlane16_swap_b32 %0, %1" : "+v"(m2), "+v"(n2));
      asm("v_permlane16_swap_b32 %0, %1" : "+v"(m3), "+v"(n3));
      pb0[qb] = (u32x4){ m0, m1, n0, n1 };
      pb1[qb] = (u32x4){ m2, m3, n2, n3 };
    }

    // O^T += V^T_tile @ P ; l += ones @ P
    __builtin_amdgcn_s_setprio(1);
    const char* cV = (const char*)VTs[cur];
#pragma unroll
    for (int db = 0; db < 4; ++db) {
      const char* vp = cV + db * 2048;
      u32x4 v0 = *(const u32x4*)(vp + A0);
      u32x4 v1 = *(const u32x4*)(vp + A1);
      oa[0][db] = MFMA16(asf16(v0), asf16(pb0[0]), oa[0][db]);
      oa[0][db] = MFMA16(asf16(v1), asf16(pb1[0]), oa[0][db]);
      oa[1][db] = MFMA16(asf16(v0), asf16(pb0[1]), oa[1][db]);
      oa[1][db] = MFMA16(asf16(v1), asf16(pb1[1]), oa[1][db]);
    }
    la[0] = MFMA16(asf16(ONES), asf16(pb0[0]), la[0]);
    la[0] = MFMA16(asf16(ONES), asf16(pb1[0]), la[0]);
    la[1] = MFMA16(asf16(ONES), asf16(pb0[1]), la[1]);
    la[1] = MFMA16(asf16(ONES), asf16(pb1[1]), la[1]);
    __builtin_amdgcn_s_setprio(0);

    __syncthreads();          // next tile's loads landed during compute
    cur ^= 1;
  }

  int b = bh >> 4, h = bh & 15;
#pragma unroll
  for (int qb = 0; qb < 2; ++qb) {
    float inv = 1.0f / la[qb][0];
    size_t obase = ((size_t)(b * 2048 + qw + qb * 16 + c)) * 1024 + h * 64;
#pragma unroll
    for (int db = 0; db < 4; ++db) {
      int d = db * 16 + g * 4;
      u32x2 o = { pk16(oa[qb][db][0] * inv, oa[qb][db][1] * inv),
                  pk16(oa[qb][db][2] * inv, oa[qb][db][3] * inv) };
      *(u32x2*)(Ob + obase + d) = o;
    }
  }
}

// ---------------- output projection (grid x=m-tile[64], y=n-tile[4]) ----------
__global__ __launch_bounds__(512, 4) void k_oproj(const u16* __restrict__ Ob, const u16* __restrict__ wto,
                                               const float* __restrict__ bo, float* __restrict__ out) {
  __shared__ alignas(16) u16 sA[3 * 128 * 32];
  __shared__ alignas(16) u16 sB[3 * 256 * 32];
  int m0 = blockIdx.x * 128;
  int n0 = blockIdx.y * 256;
  f32x4 acc[4][4];
  gemm_core(Ob, wto, sA, sB, m0, n0, acc);

  const int lane = threadIdx.x & 63;
  const int w = threadIdx.x >> 6;
  const int wr = w >> 2, wc = w & 3, c = lane & 15, g = lane >> 4;
#pragma unroll
  for (int mi = 0; mi < 4; ++mi) {
#pragma unroll
    for (int ni = 0; ni < 4; ++ni) {
      int ncol = n0 + wc * 64 + ni * 16 + c;
      float bcol = bo[ncol];
#pragma unroll
      for (int e = 0; e < 4; ++e) {
        int m = m0 + wr * 64 + mi * 16 + g * 4 + e;
        out[(size_t)m * 1024 + ncol] = acc[mi][ni][e] + bcol;
      }
    }
  }
}

extern "C" void kernel_launch(void* const* d_in, const int* in_sizes, int n_in,
                              void* d_out, int out_size, void* d_ws, size_t ws_size,
                              hipStream_t stream) {
  const float* x  = (const float*)d_in[0];
  const float* Wq = (const float*)d_in[1];
  const float* bq = (const float*)d_in[2];
  const float* Wk = (const float*)d_in[3];
  const float* bk = (const float*)d_in[4];
  const float* Wv = (const float*)d_in[5];
  const float* bv = (const float*)d_in[6];
  const float* Wo = (const float*)d_in[7];
  const float* bo = (const float*)d_in[8];
  float* out = (float*)d_out;
  char* ws = (char*)d_ws;

  // workspace layout (bytes); Ob aliases xb (xb dead after k_qkv)
  u16* xb  = (u16*)(ws + 0);                  // 8192*1024 fp16 = 16 MiB
  u16* Ob  = (u16*)(ws + 0);                  // alias of xb
  u16* wtq = (u16*)(ws + 16777216);           // 2 MiB each
  u16* wtk = (u16*)(ws + 18874368);
  u16* wtv = (u16*)(ws + 20971520);
  u16* wto = (u16*)(ws + 23068672);
  u16* Qb  = (u16*)(ws + 25165824);           // [bh][t][64]  (scale*log2e folded)
  u16* Kb  = (u16*)(ws + 41943040);           // [bh][t][64]
  u16* VTb = (u16*)(ws + 58720256);           // [bh][64][t]
  // total: 75,497,472 bytes

  k_prep<<<5120, 256, 0, stream>>>(x, xb, Wq, Wk, Wv, Wo, wtq, wtk, wtv, wto);
  k_qkv<<<dim3(64, 12), 512, 0, stream>>>(xb, wtq, wtk, wtv, bq, bk, bv, Qb, Kb, VTb);
  k_attn<<<1024, 256, 0, stream>>>(Qb, Kb, VTb, Ob);
  k_oproj<<<dim3(64, 4), 512, 0, stream>>>(Ob, wto, bo, out);
}

// Round 15
// 189.404 us; speedup vs baseline: 1.0003x; 1.0003x over previous
//
#include <hip/hip_runtime.h>
#include <stdint.h>

typedef _Float16 f16;
typedef _Float16 f16x8 __attribute__((ext_vector_type(8)));
typedef float    f32x4 __attribute__((ext_vector_type(4)));
typedef unsigned int u32x4 __attribute__((ext_vector_type(4)));
typedef unsigned int u32x2 __attribute__((ext_vector_type(2)));
typedef unsigned short u16;

#define MFMA16(A,B,C) __builtin_amdgcn_mfma_f32_16x16x32_f16(A,B,C,0,0,0)

__device__ __forceinline__ void gload_lds16(const void* g, void* l) {
  auto gp = reinterpret_cast<const __attribute__((address_space(1))) unsigned int*>(
      reinterpret_cast<uintptr_t>(g));
  auto lp = reinterpret_cast<__attribute__((address_space(3))) unsigned int*>(
      reinterpret_cast<uintptr_t>(l));
  __builtin_amdgcn_global_load_lds(gp, lp, 16, 0, 0);
}

// round-to-nearest fp16 pack (precision-relevant conversions)
__device__ __forceinline__ unsigned pk16(float a, float b) {
  unsigned short ua = __builtin_bit_cast(unsigned short, (f16)a);
  unsigned short ub = __builtin_bit_cast(unsigned short, (f16)b);
  return ((unsigned)ub << 16) | (unsigned)ua;
}
// single-instruction RTZ pack (P values in attn hot path)
__device__ __forceinline__ unsigned pk2rtz(float a, float b) {
  return __builtin_bit_cast(unsigned, __builtin_amdgcn_cvt_pkrtz(a, b));
}
// 2^x via v_exp_f32
__device__ __forceinline__ float ex2(float x) {
  float r; asm("v_exp_f32 %0, %1" : "=v"(r) : "v"(x)); return r;
}
__device__ __forceinline__ f16x8 asf16(u32x4 v) { return __builtin_bit_cast(f16x8, v); }

#define LOG2E 1.44269504088896f

// ---------------- prep: fp32->fp16 convert (blocks 0..2047, 16 floats/thread)
// + weight transpose/convert (blocks 2048..3071) in ONE launch ----------------
// This round's only change: convert path widened 8 -> 16 floats/thread
// (64B read / 32B write per lane), halving convert blocks 4096 -> 2048.
// Per-element numerics identical (same pk16).
__global__ __launch_bounds__(256) void k_prep(const float* __restrict__ x, u16* __restrict__ xb,
                                              const float* __restrict__ Wq, const float* __restrict__ Wk,
                                              const float* __restrict__ Wv, const float* __restrict__ Wo,
                                              u16* __restrict__ WTq, u16* __restrict__ WTk,
                                              u16* __restrict__ WTv, u16* __restrict__ WTo) {
  __shared__ float tile[64][65];
  int tid = threadIdx.x;
  if (blockIdx.x < 2048) {
    int i = blockIdx.x * 256 + tid;          // i < 524288; 16 floats each
    const float4* p = (const float4*)x + (size_t)i * 4;
    float4 a = p[0], b = p[1], c4 = p[2], d4 = p[3];
    u32x4 o0 = { pk16(a.x, a.y), pk16(a.z, a.w), pk16(b.x, b.y), pk16(b.z, b.w) };
    u32x4 o1 = { pk16(c4.x, c4.y), pk16(c4.z, c4.w), pk16(d4.x, d4.y), pk16(d4.z, d4.w) };
    u32x4* op = (u32x4*)xb + (size_t)i * 2;
    op[0] = o0;
    op[1] = o1;
    return;
  }
  int bid = blockIdx.x - 2048;               // [0,1024)
  int z = bid >> 8;
  const float* W = (z == 0) ? Wq : (z == 1) ? Wk : (z == 2) ? Wv : Wo;
  u16* WT = (z == 0) ? WTq : (z == 1) ? WTk : (z == 2) ? WTv : WTo;
  int r0 = ((bid >> 4) & 15) * 64, c0 = (bid & 15) * 64;
#pragma unroll
  for (int i = 0; i < 4; ++i) {
    int idx = tid + i * 256;
    int row = idx >> 4, ch = (idx & 15) * 4;
    float4 v = *(const float4*)&W[(size_t)(r0 + row) * 1024 + c0 + ch];
    tile[row][ch + 0] = v.x; tile[row][ch + 1] = v.y;
    tile[row][ch + 2] = v.z; tile[row][ch + 3] = v.w;
  }
  __syncthreads();
#pragma unroll
  for (int i = 0; i < 4; ++i) {
    int idx = tid + i * 256;
    int orow = idx >> 4, ch = (idx & 15) * 4;
    u32x2 o = { pk16(tile[ch + 0][orow], tile[ch + 1][orow]),
                pk16(tile[ch + 2][orow], tile[ch + 3][orow]) };
    *(u32x2*)&WT[(size_t)(c0 + orow) * 1024 + r0 + ch] = o;
  }
}

// ---------------- shared GEMM mainloop: 3-stage pipeline, counted vmcnt --------
// Round-6-verified: 128x256 tile, 8 waves, 3-buffer rotation, distance-2
// prefetch, ONE counted vmcnt + ONE barrier per K-tile.
// LDS: A [128 rows][32 k] (8KB/buf), B [256 rows][32 k] (16KB/buf), x3 = 72KB.
// 64B rows, 4x16B chunks, chunk swizzle ch^((row>>1)&3).
__device__ __forceinline__ void gemm_core(const u16* __restrict__ A, const u16* __restrict__ B,
                                          u16* sA, u16* sB, int m0, int n0, f32x4 acc[4][4]) {
  const int tid = threadIdx.x;               // [0,512)
  const int lane = tid & 63;
  const int w = tid >> 6;                    // [0,8)
  const int wr = w >> 2, wc = w & 3;         // 2m x 4n wave grid
  const int c = lane & 15, g = lane >> 4;
#pragma unroll
  for (int i = 0; i < 4; ++i)
#pragma unroll
    for (int j = 0; j < 4; ++j) acc[i][j] = (f32x4){0.f, 0.f, 0.f, 0.f};

  auto stage = [&](int buf, int kt) {
    {  // A: 128 rows x 32k = 8KB, 1 load/thread
      int L = tid * 16;
      int row = L >> 6;
      int chl = (L >> 4) & 3;
      int chg = chl ^ ((row >> 1) & 3);      // inverse-swizzled global source
      gload_lds16(A + (size_t)(m0 + row) * 1024 + kt + chg * 8, (char*)sA + buf * 8192 + L);
    }
#pragma unroll
    for (int j = 0; j < 2; ++j) {  // B: 256 rows x 32k = 16KB, 2 loads/thread
      int L = j * 8192 + tid * 16;
      int row = L >> 6;
      int chl = (L >> 4) & 3;
      int chg = chl ^ ((row >> 1) & 3);
      gload_lds16(B + (size_t)(n0 + row) * 1024 + kt + chg * 8, (char*)sB + buf * 16384 + L);
    }
  };

  stage(0, 0);
  stage(1, 32);
  int cur = 0;
  for (int kt = 0; kt < 1024; kt += 32) {
    if (kt < 1024 - 32) {
      asm volatile("s_waitcnt vmcnt(3)" ::: "memory");   // tile t done; t+1 in flight
    } else {
      asm volatile("s_waitcnt vmcnt(0)" ::: "memory");   // tail: drain last tile
    }
    __builtin_amdgcn_s_barrier();
    if (kt + 64 < 1024) {
      int nb = cur + 2; if (nb >= 3) nb -= 3;
      stage(nb, kt + 64);
    }
    const char* cA = (const char*)sA + cur * 8192;
    const char* cB = (const char*)sB + cur * 16384;
    u32x4 av[4], bv[4];
#pragma unroll
    for (int mi = 0; mi < 4; ++mi) {
      int row = wr * 64 + mi * 16 + c;
      av[mi] = *(const u32x4*)(cA + row * 64 + ((g ^ ((row >> 1) & 3)) << 4));
    }
#pragma unroll
    for (int ni = 0; ni < 4; ++ni) {
      int row = wc * 64 + ni * 16 + c;
      bv[ni] = *(const u32x4*)(cB + row * 64 + ((g ^ ((row >> 1) & 3)) << 4));
    }
#pragma unroll
    for (int mi = 0; mi < 4; ++mi)
#pragma unroll
      for (int ni = 0; ni < 4; ++ni)
        acc[mi][ni] = MFMA16(asf16(av[mi]), asf16(bv[ni]), acc[mi][ni]);
    cur = (cur == 2) ? 0 : cur + 1;
  }
}

// ---------------- QKV projection (grid x=m-tile[64], y=nt[12]) ----------------
__global__ __launch_bounds__(512, 4) void k_qkv(const u16* __restrict__ xb,
                                             const u16* __restrict__ wtq, const u16* __restrict__ wtk,
                                             const u16* __restrict__ wtv,
                                             const float* __restrict__ bq, const float* __restrict__ bk,
                                             const float* __restrict__ bv,
                                             u16* __restrict__ Qb, u16* __restrict__ Kb,
                                             u16* __restrict__ VTb) {
  __shared__ alignas(16) u16 sA[3 * 128 * 32];
  __shared__ alignas(16) u16 sB[3 * 256 * 32];
  int m0 = blockIdx.x * 128;
  int nt = blockIdx.y;                       // [0,12)
  int wsel = nt >> 2;
  int n0 = (nt & 3) * 256;
  const u16* WT = (wsel == 0) ? wtq : (wsel == 1) ? wtk : wtv;
  const float* bias = (wsel == 0) ? bq : (wsel == 1) ? bk : bv;
  f32x4 acc[4][4];
  gemm_core(xb, WT, sA, sB, m0, n0, acc);

  const int lane = threadIdx.x & 63;
  const int w = threadIdx.x >> 6;
  const int wr = w >> 2, wc = w & 3, c = lane & 15, g = lane >> 4;
#pragma unroll
  for (int mi = 0; mi < 4; ++mi) {
#pragma unroll
    for (int ni = 0; ni < 4; ++ni) {
      int ncol = n0 + wc * 64 + ni * 16 + c;
      float bcol = bias[ncol];
      int h = ncol >> 6, d = ncol & 63;
#pragma unroll
      for (int e = 0; e < 4; ++e) {
        int m = m0 + wr * 64 + mi * 16 + g * 4 + e;
        int b = m >> 11, t = m & 2047;
        int bh = (b << 4) | h;
        float val = acc[mi][ni][e] + bcol;
        if (wsel == 0) {
          // fold 1/sqrt(d_k) AND log2(e) into Q (softmax runs in exp2 domain)
          Qb[((size_t)bh * 2048 + t) * 64 + d] = __builtin_bit_cast(u16, (f16)(val * (0.125f * LOG2E)));
        } else if (wsel == 1) {
          Kb[((size_t)bh * 2048 + t) * 64 + d] = __builtin_bit_cast(u16, (f16)val);
        } else {
          VTb[((size_t)bh * 64 + d) * 2048 + t] = __builtin_bit_cast(u16, (f16)val);
        }
      }
    }
  }
}

// ---------------- flash attention: 4 waves x 32 q-rows, KVBLK=64, dbuf ----------
// Verified round-3/round-6 kernel, byte-identical (pair-wise permlane16_swap
// network with sigma-permuted V^T chunk staging). THREE restructure attempts
// (R1 compile-time-unrolled buffers, R7 deferred-PV, R13 8-wave co-staging)
// all failed numerically despite provably-equivalent dataflow — this body and
// its compilation context are load-bearing; do not modify.
__global__ __launch_bounds__(256) void k_attn(const u16* __restrict__ Qb, const u16* __restrict__ Kb,
                                              const u16* __restrict__ VTb, u16* __restrict__ Ob) {
  __shared__ alignas(16) u16 Ks[2][64 * 64];
  __shared__ alignas(16) u16 VTs[2][64 * 64];
  const int tid = threadIdx.x, lane = tid & 63, w = tid >> 6;
  const int c = lane & 15, g = lane >> 4;
  // XCD swizzle: lin = bh_local*128 + qblk*8 + xcd  (bijective over [0,1024))
  const int lin = blockIdx.x;
  const int bh = (lin & 7) * 8 + (lin >> 7);
  const int qblk = (lin >> 3) & 15;
  const int qw = qblk * 128 + w * 32;           // wave's 32-row q base
  const size_t kbase = (size_t)bh * 2048 * 64;  // K rows base (elems)
  const size_t vbase = (size_t)bh * 64 * 2048;  // VT rows base

  // Q fragments (B-operand layout): qa[qb*2+0]: row qw+qb*16+c elems g*8..+7;
  //                                 qa[qb*2+1]: same row, elems 32+g*8..+7
  u32x4 qa0 = *(const u32x4*)(Qb + ((size_t)bh * 2048 + qw + c) * 64 + g * 8);
  u32x4 qa1 = *(const u32x4*)(Qb + ((size_t)bh * 2048 + qw + c) * 64 + 32 + g * 8);
  u32x4 qa2 = *(const u32x4*)(Qb + ((size_t)bh * 2048 + qw + 16 + c) * 64 + g * 8);
  u32x4 qa3 = *(const u32x4*)(Qb + ((size_t)bh * 2048 + qw + 16 + c) * 64 + 32 + g * 8);

  const u32x4 ONES = { 0x3C003C00u, 0x3C003C00u, 0x3C003C00u, 0x3C003C00u }; // f16 1.0 x8

  // ---- hoisted staging addresses (per-lane, loop-invariant bases) ----
  const int L0 = tid * 16, L1 = 4096 + tid * 16;
  const int row0 = L0 >> 7, row1 = L1 >> 7;
  const int chg0 = ((L0 >> 4) & 7) ^ (row0 & 7);
  const int chg1 = ((L1 >> 4) & 7) ^ (row1 & 7);
  // VT chunk permutation sigma (swap chunk-index bits 0 and 1)
  const int vchg0 = (chg0 & 4) | ((chg0 & 1) << 1) | ((chg0 >> 1) & 1);
  const int vchg1 = (chg1 & 4) | ((chg1 & 1) << 1) | ((chg1 >> 1) & 1);
  const u16* kg0 = Kb + kbase + (size_t)row0 * 64 + chg0 * 8;
  const u16* kg1 = Kb + kbase + (size_t)row1 * 64 + chg1 * 8;
  const u16* vg0 = VTb + vbase + (size_t)row0 * 2048 + vchg0 * 8;
  const u16* vg1 = VTb + vbase + (size_t)row1 * 2048 + vchg1 * 8;

  auto stage = [&](int buf, int kt) {
    gload_lds16(kg0 + (size_t)kt * 64, (char*)Ks[buf] + L0);
    gload_lds16(kg1 + (size_t)kt * 64, (char*)Ks[buf] + L1);
    gload_lds16(vg0 + kt,              (char*)VTs[buf] + L0);
    gload_lds16(vg1 + kt,              (char*)VTs[buf] + L1);
  };

  // ---- hoisted LDS read offsets (kb/db-invariant swizzle) ----
  const int A0 = c * 128 + ((g ^ (c & 7)) << 4);
  const int A1 = A0 ^ 0x40;                     // (g+4) chunk partner

  f32x4 oa[2][4];
  f32x4 la[2];
#pragma unroll
  for (int qb = 0; qb < 2; ++qb) {
    la[qb] = (f32x4){0.f, 0.f, 0.f, 0.f};
#pragma unroll
    for (int i = 0; i < 4; ++i) oa[qb][i] = (f32x4){0.f, 0.f, 0.f, 0.f};
  }

  stage(0, 0);
  __syncthreads();
  int cur = 0;
  for (int kt = 0; kt < 2048; kt += 64) {
    if (kt + 64 < 2048) stage(cur ^ 1, kt + 64);  // prefetch next K/V tile

    // QK^T (swapped operands) -> exp2 -> packed fp16 P, per q-block
    // wds[qb][kb*2+j] packs P[k=kt+kb*16+g*4+{2j,2j+1}][q=qw+qb*16+c]
    unsigned wds[2][8];
    __builtin_amdgcn_s_setprio(1);
    const char* cK = (const char*)Ks[cur];
#pragma unroll
    for (int kb = 0; kb < 4; ++kb) {
      const char* bp = cK + kb * 2048;
      u32x4 k0 = *(const u32x4*)(bp + A0);
      u32x4 k1 = *(const u32x4*)(bp + A1);
      f32x4 z0 = (f32x4){0.f, 0.f, 0.f, 0.f};
      z0 = MFMA16(asf16(k0), asf16(qa0), z0);
      z0 = MFMA16(asf16(k1), asf16(qa1), z0);
      wds[0][kb * 2]     = pk2rtz(ex2(z0[0]), ex2(z0[1]));
      wds[0][kb * 2 + 1] = pk2rtz(ex2(z0[2]), ex2(z0[3]));
      f32x4 z1 = (f32x4){0.f, 0.f, 0.f, 0.f};
      z1 = MFMA16(asf16(k0), asf16(qa2), z1);
      z1 = MFMA16(asf16(k1), asf16(qa3), z1);
      wds[1][kb * 2]     = pk2rtz(ex2(z1[0]), ex2(z1[1]));
      wds[1][kb * 2 + 1] = pk2rtz(ex2(z1[2]), ex2(z1[3]));
    }
    __builtin_amdgcn_s_setprio(0);

    // redistribute P -> B-fragment layout: pair-wise permlane16_swap only.
    // swap16(w0,w2): m'=[w0.g0,w2.g0,w0.g2,w2.g2] = B-word0, n' = B-word2
    // (valid against the sigma-permuted V^T chunk order staged above).
    u32x4 pb0[2], pb1[2];
#pragma unroll
    for (int qb = 0; qb < 2; ++qb) {
      unsigned m0 = wds[qb][0], n0 = wds[qb][2];
      unsigned m1 = wds[qb][1], n1 = wds[qb][3];
      unsigned m2 = wds[qb][4], n2 = wds[qb][6];
      unsigned m3 = wds[qb][5], n3 = wds[qb][7];
      asm("v_permlane16_swap_b32 %0, %1" : "+v"(m0), "+v"(n0));
      asm("v_permlane16_swap_b32 %0, %1" : "+v"(m1), "+v"(n1));
      asm("v_permlane16_swap_b32 %0, %1" : "+v"(m2), "+v"(n2));
      asm("v_permlane16_swap_b32 %0, %1" : "+v"(m3), "+v"(n3));
      pb0[qb] = (u32x4){ m0, m1, n0, n1 };
      pb1[qb] = (u32x4){ m2, m3, n2, n3 };
    }

    // O^T += V^T_tile @ P ; l += ones @ P
    __builtin_amdgcn_s_setprio(1);
    const char* cV = (const char*)VTs[cur];
#pragma unroll
    for (int db = 0; db < 4; ++db) {
      const char* vp = cV + db * 2048;
      u32x4 v0 = *(const u32x4*)(vp + A0);
      u32x4 v1 = *(const u32x4*)(vp + A1);
      oa[0][db] = MFMA16(asf16(v0), asf16(pb0[0]), oa[0][db]);
      oa[0][db] = MFMA16(asf16(v1), asf16(pb1[0]), oa[0][db]);
      oa[1][db] = MFMA16(asf16(v0), asf16(pb0[1]), oa[1][db]);
      oa[1][db] = MFMA16(asf16(v1), asf16(pb1[1]), oa[1][db]);
    }
    la[0] = MFMA16(asf16(ONES), asf16(pb0[0]), la[0]);
    la[0] = MFMA16(asf16(ONES), asf16(pb1[0]), la[0]);
    la[1] = MFMA16(asf16(ONES), asf16(pb0[1]), la[1]);
    la[1] = MFMA16(asf16(ONES), asf16(pb1[1]), la[1]);
    __builtin_amdgcn_s_setprio(0);

    __syncthreads();          // next tile's loads landed during compute
    cur ^= 1;
  }

  int b = bh >> 4, h = bh & 15;
#pragma unroll
  for (int qb = 0; qb < 2; ++qb) {
    float inv = 1.0f / la[qb][0];
    size_t obase = ((size_t)(b * 2048 + qw + qb * 16 + c)) * 1024 + h * 64;
#pragma unroll
    for (int db = 0; db < 4; ++db) {
      int d = db * 16 + g * 4;
      u32x2 o = { pk16(oa[qb][db][0] * inv, oa[qb][db][1] * inv),
                  pk16(oa[qb][db][2] * inv, oa[qb][db][3] * inv) };
      *(u32x2*)(Ob + obase + d) = o;
    }
  }
}

// ---------------- output projection (grid x=m-tile[64], y=n-tile[4]) ----------
__global__ __launch_bounds__(512, 4) void k_oproj(const u16* __restrict__ Ob, const u16* __restrict__ wto,
                                               const float* __restrict__ bo, float* __restrict__ out) {
  __shared__ alignas(16) u16 sA[3 * 128 * 32];
  __shared__ alignas(16) u16 sB[3 * 256 * 32];
  int m0 = blockIdx.x * 128;
  int n0 = blockIdx.y * 256;
  f32x4 acc[4][4];
  gemm_core(Ob, wto, sA, sB, m0, n0, acc);

  const int lane = threadIdx.x & 63;
  const int w = threadIdx.x >> 6;
  const int wr = w >> 2, wc = w & 3, c = lane & 15, g = lane >> 4;
#pragma unroll
  for (int mi = 0; mi < 4; ++mi) {
#pragma unroll
    for (int ni = 0; ni < 4; ++ni) {
      int ncol = n0 + wc * 64 + ni * 16 + c;
      float bcol = bo[ncol];
#pragma unroll
      for (int e = 0; e < 4; ++e) {
        int m = m0 + wr * 64 + mi * 16 + g * 4 + e;
        out[(size_t)m * 1024 + ncol] = acc[mi][ni][e] + bcol;
      }
    }
  }
}

extern "C" void kernel_launch(void* const* d_in, const int* in_sizes, int n_in,
                              void* d_out, int out_size, void* d_ws, size_t ws_size,
                              hipStream_t stream) {
  const float* x  = (const float*)d_in[0];
  const float* Wq = (const float*)d_in[1];
  const float* bq = (const float*)d_in[2];
  const float* Wk = (const float*)d_in[3];
  const float* bk = (const float*)d_in[4];
  const float* Wv = (const float*)d_in[5];
  const float* bv = (const float*)d_in[6];
  const float* Wo = (const float*)d_in[7];
  const float* bo = (const float*)d_in[8];
  float* out = (float*)d_out;
  char* ws = (char*)d_ws;

  // workspace layout (bytes); Ob aliases xb (xb dead after k_qkv)
  u16* xb  = (u16*)(ws + 0);                  // 8192*1024 fp16 = 16 MiB
  u16* Ob  = (u16*)(ws + 0);                  // alias of xb
  u16* wtq = (u16*)(ws + 16777216);           // 2 MiB each
  u16* wtk = (u16*)(ws + 18874368);
  u16* wtv = (u16*)(ws + 20971520);
  u16* wto = (u16*)(ws + 23068672);
  u16* Qb  = (u16*)(ws + 25165824);           // [bh][t][64]  (scale*log2e folded)
  u16* Kb  = (u16*)(ws + 41943040);           // [bh][t][64]
  u16* VTb = (u16*)(ws + 58720256);           // [bh][64][t]
  // total: 75,497,472 bytes

  k_prep<<<3072, 256, 0, stream>>>(x, xb, Wq, Wk, Wv, Wo, wtq, wtk, wtv, wto);
  k_qkv<<<dim3(64, 12), 512, 0, stream>>>(xb, wtq, wtk, wtv, bq, bk, bv, Qb, Kb, VTb);
  k_attn<<<1024, 256, 0, stream>>>(Qb, Kb, VTb, Ob);
  k_oproj<<<dim3(64, 4), 512, 0, stream>>>(Ob, wto, bo, out);
}

// Round 16
// 178.991 us; speedup vs baseline: 1.0585x; 1.0582x over previous
//
#include <hip/hip_runtime.h>
#include <stdint.h>

typedef _Float16 f16;
typedef _Float16 f16x8 __attribute__((ext_vector_type(8)));
typedef float    f32x4 __attribute__((ext_vector_type(4)));
typedef unsigned int u32x4 __attribute__((ext_vector_type(4)));
typedef unsigned int u32x2 __attribute__((ext_vector_type(2)));
typedef unsigned short u16;

#define MFMA16(A,B,C) __builtin_amdgcn_mfma_f32_16x16x32_f16(A,B,C,0,0,0)

__device__ __forceinline__ void gload_lds16(const void* g, void* l) {
  auto gp = reinterpret_cast<const __attribute__((address_space(1))) unsigned int*>(
      reinterpret_cast<uintptr_t>(g));
  auto lp = reinterpret_cast<__attribute__((address_space(3))) unsigned int*>(
      reinterpret_cast<uintptr_t>(l));
  __builtin_amdgcn_global_load_lds(gp, lp, 16, 0, 0);
}

// round-to-nearest fp16 pack (precision-relevant conversions)
__device__ __forceinline__ unsigned pk16(float a, float b) {
  unsigned short ua = __builtin_bit_cast(unsigned short, (f16)a);
  unsigned short ub = __builtin_bit_cast(unsigned short, (f16)b);
  return ((unsigned)ub << 16) | (unsigned)ua;
}
// single-instruction RTZ pack (P values in attn hot path)
__device__ __forceinline__ unsigned pk2rtz(float a, float b) {
  return __builtin_bit_cast(unsigned, __builtin_amdgcn_cvt_pkrtz(a, b));
}
// 2^x via v_exp_f32
__device__ __forceinline__ float ex2(float x) {
  float r; asm("v_exp_f32 %0, %1" : "=v"(r) : "v"(x)); return r;
}
__device__ __forceinline__ f16x8 asf16(u32x4 v) { return __builtin_bit_cast(f16x8, v); }

#define LOG2E 1.44269504088896f

// ---------------- prep: fp32->fp16 convert (blocks 0..2047, 16 floats/thread)
// + weight transpose/convert (blocks 2048..3071) in ONE launch ----------------
__global__ __launch_bounds__(256) void k_prep(const float* __restrict__ x, u16* __restrict__ xb,
                                              const float* __restrict__ Wq, const float* __restrict__ Wk,
                                              const float* __restrict__ Wv, const float* __restrict__ Wo,
                                              u16* __restrict__ WTq, u16* __restrict__ WTk,
                                              u16* __restrict__ WTv, u16* __restrict__ WTo) {
  __shared__ float tile[64][65];
  int tid = threadIdx.x;
  if (blockIdx.x < 2048) {
    int i = blockIdx.x * 256 + tid;          // i < 524288; 16 floats each
    const float4* p = (const float4*)x + (size_t)i * 4;
    float4 a = p[0], b = p[1], c4 = p[2], d4 = p[3];
    u32x4 o0 = { pk16(a.x, a.y), pk16(a.z, a.w), pk16(b.x, b.y), pk16(b.z, b.w) };
    u32x4 o1 = { pk16(c4.x, c4.y), pk16(c4.z, c4.w), pk16(d4.x, d4.y), pk16(d4.z, d4.w) };
    u32x4* op = (u32x4*)xb + (size_t)i * 2;
    op[0] = o0;
    op[1] = o1;
    return;
  }
  int bid = blockIdx.x - 2048;               // [0,1024)
  int z = bid >> 8;
  const float* W = (z == 0) ? Wq : (z == 1) ? Wk : (z == 2) ? Wv : Wo;
  u16* WT = (z == 0) ? WTq : (z == 1) ? WTk : (z == 2) ? WTv : WTo;
  int r0 = ((bid >> 4) & 15) * 64, c0 = (bid & 15) * 64;
#pragma unroll
  for (int i = 0; i < 4; ++i) {
    int idx = tid + i * 256;
    int row = idx >> 4, ch = (idx & 15) * 4;
    float4 v = *(const float4*)&W[(size_t)(r0 + row) * 1024 + c0 + ch];
    tile[row][ch + 0] = v.x; tile[row][ch + 1] = v.y;
    tile[row][ch + 2] = v.z; tile[row][ch + 3] = v.w;
  }
  __syncthreads();
#pragma unroll
  for (int i = 0; i < 4; ++i) {
    int idx = tid + i * 256;
    int orow = idx >> 4, ch = (idx & 15) * 4;
    u32x2 o = { pk16(tile[ch + 0][orow], tile[ch + 1][orow]),
                pk16(tile[ch + 2][orow], tile[ch + 3][orow]) };
    *(u32x2*)&WT[(size_t)(c0 + orow) * 1024 + r0 + ch] = o;
  }
}

// ---------------- shared GEMM mainloop: 3-stage pipeline, counted vmcnt --------
// Round-6-verified: 128x256 tile, 8 waves, 3-buffer rotation, distance-2
// prefetch, ONE counted vmcnt + ONE barrier per K-tile.
// LDS: A [128 rows][32 k] (8KB/buf), B [256 rows][32 k] (16KB/buf), x3 = 72KB.
// 64B rows, 4x16B chunks, chunk swizzle ch^((row>>1)&3).
__device__ __forceinline__ void gemm_core(const u16* __restrict__ A, const u16* __restrict__ B,
                                          u16* sA, u16* sB, int m0, int n0, f32x4 acc[4][4]) {
  const int tid = threadIdx.x;               // [0,512)
  const int lane = tid & 63;
  const int w = tid >> 6;                    // [0,8)
  const int wr = w >> 2, wc = w & 3;         // 2m x 4n wave grid
  const int c = lane & 15, g = lane >> 4;
#pragma unroll
  for (int i = 0; i < 4; ++i)
#pragma unroll
    for (int j = 0; j < 4; ++j) acc[i][j] = (f32x4){0.f, 0.f, 0.f, 0.f};

  auto stage = [&](int buf, int kt) {
    {  // A: 128 rows x 32k = 8KB, 1 load/thread
      int L = tid * 16;
      int row = L >> 6;
      int chl = (L >> 4) & 3;
      int chg = chl ^ ((row >> 1) & 3);      // inverse-swizzled global source
      gload_lds16(A + (size_t)(m0 + row) * 1024 + kt + chg * 8, (char*)sA + buf * 8192 + L);
    }
#pragma unroll
    for (int j = 0; j < 2; ++j) {  // B: 256 rows x 32k = 16KB, 2 loads/thread
      int L = j * 8192 + tid * 16;
      int row = L >> 6;
      int chl = (L >> 4) & 3;
      int chg = chl ^ ((row >> 1) & 3);
      gload_lds16(B + (size_t)(n0 + row) * 1024 + kt + chg * 8, (char*)sB + buf * 16384 + L);
    }
  };

  stage(0, 0);
  stage(1, 32);
  int cur = 0;
  for (int kt = 0; kt < 1024; kt += 32) {
    if (kt < 1024 - 32) {
      asm volatile("s_waitcnt vmcnt(3)" ::: "memory");   // tile t done; t+1 in flight
    } else {
      asm volatile("s_waitcnt vmcnt(0)" ::: "memory");   // tail: drain last tile
    }
    __builtin_amdgcn_s_barrier();
    if (kt + 64 < 1024) {
      int nb = cur + 2; if (nb >= 3) nb -= 3;
      stage(nb, kt + 64);
    }
    const char* cA = (const char*)sA + cur * 8192;
    const char* cB = (const char*)sB + cur * 16384;
    u32x4 av[4], bv[4];
#pragma unroll
    for (int mi = 0; mi < 4; ++mi) {
      int row = wr * 64 + mi * 16 + c;
      av[mi] = *(const u32x4*)(cA + row * 64 + ((g ^ ((row >> 1) & 3)) << 4));
    }
#pragma unroll
    for (int ni = 0; ni < 4; ++ni) {
      int row = wc * 64 + ni * 16 + c;
      bv[ni] = *(const u32x4*)(cB + row * 64 + ((g ^ ((row >> 1) & 3)) << 4));
    }
#pragma unroll
    for (int mi = 0; mi < 4; ++mi)
#pragma unroll
      for (int ni = 0; ni < 4; ++ni)
        acc[mi][ni] = MFMA16(asf16(av[mi]), asf16(bv[ni]), acc[mi][ni]);
    cur = (cur == 2) ? 0 : cur + 1;
  }
}

// ---------------- QKV projection (grid x=m-tile[64], y=nt[12]) ----------------
// This round's only change: the V^T epilogue packs the 4 consecutive-t u16
// stores (e=0..3; m0+wr*64+mi*16+g*4 is 4-aligned so t0..t0+3 are contiguous,
// same b) into ONE 8-byte store -> 4x fewer scattered store transactions.
// Same values, same addresses, same thread: numerics and race profile
// identical to the verified kernel.
__global__ __launch_bounds__(512, 4) void k_qkv(const u16* __restrict__ xb,
                                             const u16* __restrict__ wtq, const u16* __restrict__ wtk,
                                             const u16* __restrict__ wtv,
                                             const float* __restrict__ bq, const float* __restrict__ bk,
                                             const float* __restrict__ bv,
                                             u16* __restrict__ Qb, u16* __restrict__ Kb,
                                             u16* __restrict__ VTb) {
  __shared__ alignas(16) u16 sA[3 * 128 * 32];
  __shared__ alignas(16) u16 sB[3 * 256 * 32];
  int m0 = blockIdx.x * 128;
  int nt = blockIdx.y;                       // [0,12)
  int wsel = nt >> 2;
  int n0 = (nt & 3) * 256;
  const u16* WT = (wsel == 0) ? wtq : (wsel == 1) ? wtk : wtv;
  const float* bias = (wsel == 0) ? bq : (wsel == 1) ? bk : bv;
  f32x4 acc[4][4];
  gemm_core(xb, WT, sA, sB, m0, n0, acc);

  const int lane = threadIdx.x & 63;
  const int w = threadIdx.x >> 6;
  const int wr = w >> 2, wc = w & 3, c = lane & 15, g = lane >> 4;
#pragma unroll
  for (int mi = 0; mi < 4; ++mi) {
#pragma unroll
    for (int ni = 0; ni < 4; ++ni) {
      int ncol = n0 + wc * 64 + ni * 16 + c;
      float bcol = bias[ncol];
      int h = ncol >> 6, d = ncol & 63;
      if (wsel == 2) {
        // V^T: 4 consecutive t positions -> one packed 8-byte store
        int m = m0 + wr * 64 + mi * 16 + g * 4;     // e=0; 4-aligned
        int b = m >> 11, t = m & 2047;
        int bh = (b << 4) | h;
        float v0 = acc[mi][ni][0] + bcol, v1 = acc[mi][ni][1] + bcol;
        float v2 = acc[mi][ni][2] + bcol, v3 = acc[mi][ni][3] + bcol;
        u32x2 o = { pk16(v0, v1), pk16(v2, v3) };
        *(u32x2*)&VTb[((size_t)bh * 64 + d) * 2048 + t] = o;
      } else {
#pragma unroll
        for (int e = 0; e < 4; ++e) {
          int m = m0 + wr * 64 + mi * 16 + g * 4 + e;
          int b = m >> 11, t = m & 2047;
          int bh = (b << 4) | h;
          float val = acc[mi][ni][e] + bcol;
          if (wsel == 0) {
            // fold 1/sqrt(d_k) AND log2(e) into Q (softmax runs in exp2 domain)
            Qb[((size_t)bh * 2048 + t) * 64 + d] = __builtin_bit_cast(u16, (f16)(val * (0.125f * LOG2E)));
          } else {
            Kb[((size_t)bh * 2048 + t) * 64 + d] = __builtin_bit_cast(u16, (f16)val);
          }
        }
      }
    }
  }
}

// ---------------- flash attention: 4 waves x 32 q-rows, KVBLK=64, dbuf ----------
// Verified round-3/round-6 kernel, byte-identical (pair-wise permlane16_swap
// network with sigma-permuted V^T chunk staging). THREE restructure attempts
// (R1 compile-time-unrolled buffers, R7 deferred-PV, R13 8-wave co-staging)
// all failed numerically despite provably-equivalent dataflow — this body and
// its compilation context are load-bearing; do not modify.
__global__ __launch_bounds__(256) void k_attn(const u16* __restrict__ Qb, const u16* __restrict__ Kb,
                                              const u16* __restrict__ VTb, u16* __restrict__ Ob) {
  __shared__ alignas(16) u16 Ks[2][64 * 64];
  __shared__ alignas(16) u16 VTs[2][64 * 64];
  const int tid = threadIdx.x, lane = tid & 63, w = tid >> 6;
  const int c = lane & 15, g = lane >> 4;
  // XCD swizzle: lin = bh_local*128 + qblk*8 + xcd  (bijective over [0,1024))
  const int lin = blockIdx.x;
  const int bh = (lin & 7) * 8 + (lin >> 7);
  const int qblk = (lin >> 3) & 15;
  const int qw = qblk * 128 + w * 32;           // wave's 32-row q base
  const size_t kbase = (size_t)bh * 2048 * 64;  // K rows base (elems)
  const size_t vbase = (size_t)bh * 64 * 2048;  // VT rows base

  // Q fragments (B-operand layout): qa[qb*2+0]: row qw+qb*16+c elems g*8..+7;
  //                                 qa[qb*2+1]: same row, elems 32+g*8..+7
  u32x4 qa0 = *(const u32x4*)(Qb + ((size_t)bh * 2048 + qw + c) * 64 + g * 8);
  u32x4 qa1 = *(const u32x4*)(Qb + ((size_t)bh * 2048 + qw + c) * 64 + 32 + g * 8);
  u32x4 qa2 = *(const u32x4*)(Qb + ((size_t)bh * 2048 + qw + 16 + c) * 64 + g * 8);
  u32x4 qa3 = *(const u32x4*)(Qb + ((size_t)bh * 2048 + qw + 16 + c) * 64 + 32 + g * 8);

  const u32x4 ONES = { 0x3C003C00u, 0x3C003C00u, 0x3C003C00u, 0x3C003C00u }; // f16 1.0 x8

  // ---- hoisted staging addresses (per-lane, loop-invariant bases) ----
  const int L0 = tid * 16, L1 = 4096 + tid * 16;
  const int row0 = L0 >> 7, row1 = L1 >> 7;
  const int chg0 = ((L0 >> 4) & 7) ^ (row0 & 7);
  const int chg1 = ((L1 >> 4) & 7) ^ (row1 & 7);
  // VT chunk permutation sigma (swap chunk-index bits 0 and 1)
  const int vchg0 = (chg0 & 4) | ((chg0 & 1) << 1) | ((chg0 >> 1) & 1);
  const int vchg1 = (chg1 & 4) | ((chg1 & 1) << 1) | ((chg1 >> 1) & 1);
  const u16* kg0 = Kb + kbase + (size_t)row0 * 64 + chg0 * 8;
  const u16* kg1 = Kb + kbase + (size_t)row1 * 64 + chg1 * 8;
  const u16* vg0 = VTb + vbase + (size_t)row0 * 2048 + vchg0 * 8;
  const u16* vg1 = VTb + vbase + (size_t)row1 * 2048 + vchg1 * 8;

  auto stage = [&](int buf, int kt) {
    gload_lds16(kg0 + (size_t)kt * 64, (char*)Ks[buf] + L0);
    gload_lds16(kg1 + (size_t)kt * 64, (char*)Ks[buf] + L1);
    gload_lds16(vg0 + kt,              (char*)VTs[buf] + L0);
    gload_lds16(vg1 + kt,              (char*)VTs[buf] + L1);
  };

  // ---- hoisted LDS read offsets (kb/db-invariant swizzle) ----
  const int A0 = c * 128 + ((g ^ (c & 7)) << 4);
  const int A1 = A0 ^ 0x40;                     // (g+4) chunk partner

  f32x4 oa[2][4];
  f32x4 la[2];
#pragma unroll
  for (int qb = 0; qb < 2; ++qb) {
    la[qb] = (f32x4){0.f, 0.f, 0.f, 0.f};
#pragma unroll
    for (int i = 0; i < 4; ++i) oa[qb][i] = (f32x4){0.f, 0.f, 0.f, 0.f};
  }

  stage(0, 0);
  __syncthreads();
  int cur = 0;
  for (int kt = 0; kt < 2048; kt += 64) {
    if (kt + 64 < 2048) stage(cur ^ 1, kt + 64);  // prefetch next K/V tile

    // QK^T (swapped operands) -> exp2 -> packed fp16 P, per q-block
    // wds[qb][kb*2+j] packs P[k=kt+kb*16+g*4+{2j,2j+1}][q=qw+qb*16+c]
    unsigned wds[2][8];
    __builtin_amdgcn_s_setprio(1);
    const char* cK = (const char*)Ks[cur];
#pragma unroll
    for (int kb = 0; kb < 4; ++kb) {
      const char* bp = cK + kb * 2048;
      u32x4 k0 = *(const u32x4*)(bp + A0);
      u32x4 k1 = *(const u32x4*)(bp + A1);
      f32x4 z0 = (f32x4){0.f, 0.f, 0.f, 0.f};
      z0 = MFMA16(asf16(k0), asf16(qa0), z0);
      z0 = MFMA16(asf16(k1), asf16(qa1), z0);
      wds[0][kb * 2]     = pk2rtz(ex2(z0[0]), ex2(z0[1]));
      wds[0][kb * 2 + 1] = pk2rtz(ex2(z0[2]), ex2(z0[3]));
      f32x4 z1 = (f32x4){0.f, 0.f, 0.f, 0.f};
      z1 = MFMA16(asf16(k0), asf16(qa2), z1);
      z1 = MFMA16(asf16(k1), asf16(qa3), z1);
      wds[1][kb * 2]     = pk2rtz(ex2(z1[0]), ex2(z1[1]));
      wds[1][kb * 2 + 1] = pk2rtz(ex2(z1[2]), ex2(z1[3]));
    }
    __builtin_amdgcn_s_setprio(0);

    // redistribute P -> B-fragment layout: pair-wise permlane16_swap only.
    // swap16(w0,w2): m'=[w0.g0,w2.g0,w0.g2,w2.g2] = B-word0, n' = B-word2
    // (valid against the sigma-permuted V^T chunk order staged above).
    u32x4 pb0[2], pb1[2];
#pragma unroll
    for (int qb = 0; qb < 2; ++qb) {
      unsigned m0 = wds[qb][0], n0 = wds[qb][2];
      unsigned m1 = wds[qb][1], n1 = wds[qb][3];
      unsigned m2 = wds[qb][4], n2 = wds[qb][6];
      unsigned m3 = wds[qb][5], n3 = wds[qb][7];
      asm("v_permlane16_swap_b32 %0, %1" : "+v"(m0), "+v"(n0));
      asm("v_permlane16_swap_b32 %0, %1" : "+v"(m1), "+v"(n1));
      asm("v_permlane16_swap_b32 %0, %1" : "+v"(m2), "+v"(n2));
      asm("v_permlane16_swap_b32 %0, %1" : "+v"(m3), "+v"(n3));
      pb0[qb] = (u32x4){ m0, m1, n0, n1 };
      pb1[qb] = (u32x4){ m2, m3, n2, n3 };
    }

    // O^T += V^T_tile @ P ; l += ones @ P
    __builtin_amdgcn_s_setprio(1);
    const char* cV = (const char*)VTs[cur];
#pragma unroll
    for (int db = 0; db < 4; ++db) {
      const char* vp = cV + db * 2048;
      u32x4 v0 = *(const u32x4*)(vp + A0);
      u32x4 v1 = *(const u32x4*)(vp + A1);
      oa[0][db] = MFMA16(asf16(v0), asf16(pb0[0]), oa[0][db]);
      oa[0][db] = MFMA16(asf16(v1), asf16(pb1[0]), oa[0][db]);
      oa[1][db] = MFMA16(asf16(v0), asf16(pb0[1]), oa[1][db]);
      oa[1][db] = MFMA16(asf16(v1), asf16(pb1[1]), oa[1][db]);
    }
    la[0] = MFMA16(asf16(ONES), asf16(pb0[0]), la[0]);
    la[0] = MFMA16(asf16(ONES), asf16(pb1[0]), la[0]);
    la[1] = MFMA16(asf16(ONES), asf16(pb0[1]), la[1]);
    la[1] = MFMA16(asf16(ONES), asf16(pb1[1]), la[1]);
    __builtin_amdgcn_s_setprio(0);

    __syncthreads();          // next tile's loads landed during compute
    cur ^= 1;
  }

  int b = bh >> 4, h = bh & 15;
#pragma unroll
  for (int qb = 0; qb < 2; ++qb) {
    float inv = 1.0f / la[qb][0];
    size_t obase = ((size_t)(b * 2048 + qw + qb * 16 + c)) * 1024 + h * 64;
#pragma unroll
    for (int db = 0; db < 4; ++db) {
      int d = db * 16 + g * 4;
      u32x2 o = { pk16(oa[qb][db][0] * inv, oa[qb][db][1] * inv),
                  pk16(oa[qb][db][2] * inv, oa[qb][db][3] * inv) };
      *(u32x2*)(Ob + obase + d) = o;
    }
  }
}

// ---------------- output projection (grid x=m-tile[64], y=n-tile[4]) ----------
__global__ __launch_bounds__(512, 4) void k_oproj(const u16* __restrict__ Ob, const u16* __restrict__ wto,
                                               const float* __restrict__ bo, float* __restrict__ out) {
  __shared__ alignas(16) u16 sA[3 * 128 * 32];
  __shared__ alignas(16) u16 sB[3 * 256 * 32];
  int m0 = blockIdx.x * 128;
  int n0 = blockIdx.y * 256;
  f32x4 acc[4][4];
  gemm_core(Ob, wto, sA, sB, m0, n0, acc);

  const int lane = threadIdx.x & 63;
  const int w = threadIdx.x >> 6;
  const int wr = w >> 2, wc = w & 3, c = lane & 15, g = lane >> 4;
#pragma unroll
  for (int mi = 0; mi < 4; ++mi) {
#pragma unroll
    for (int ni = 0; ni < 4; ++ni) {
      int ncol = n0 + wc * 64 + ni * 16 + c;
      float bcol = bo[ncol];
#pragma unroll
      for (int e = 0; e < 4; ++e) {
        int m = m0 + wr * 64 + mi * 16 + g * 4 + e;
        out[(size_t)m * 1024 + ncol] = acc[mi][ni][e] + bcol;
      }
    }
  }
}

extern "C" void kernel_launch(void* const* d_in, const int* in_sizes, int n_in,
                              void* d_out, int out_size, void* d_ws, size_t ws_size,
                              hipStream_t stream) {
  const float* x  = (const float*)d_in[0];
  const float* Wq = (const float*)d_in[1];
  const float* bq = (const float*)d_in[2];
  const float* Wk = (const float*)d_in[3];
  const float* bk = (const float*)d_in[4];
  const float* Wv = (const float*)d_in[5];
  const float* bv = (const float*)d_in[6];
  const float* Wo = (const float*)d_in[7];
  const float* bo = (const float*)d_in[8];
  float* out = (float*)d_out;
  char* ws = (char*)d_ws;

  // workspace layout (bytes); Ob aliases xb (xb dead after k_qkv)
  u16* xb  = (u16*)(ws + 0);                  // 8192*1024 fp16 = 16 MiB
  u16* Ob  = (u16*)(ws + 0);                  // alias of xb
  u16* wtq = (u16*)(ws + 16777216);           // 2 MiB each
  u16* wtk = (u16*)(ws + 18874368);
  u16* wtv = (u16*)(ws + 20971520);
  u16* wto = (u16*)(ws + 23068672);
  u16* Qb  = (u16*)(ws + 25165824);           // [bh][t][64]  (scale*log2e folded)
  u16* Kb  = (u16*)(ws + 41943040);           // [bh][t][64]
  u16* VTb = (u16*)(ws + 58720256);           // [bh][64][t]
  // total: 75,497,472 bytes

  k_prep<<<3072, 256, 0, stream>>>(x, xb, Wq, Wk, Wv, Wo, wtq, wtk, wtv, wto);
  k_qkv<<<dim3(64, 12), 512, 0, stream>>>(xb, wtq, wtk, wtv, bq, bk, bv, Qb, Kb, VTb);
  k_attn<<<1024, 256, 0, stream>>>(Qb, Kb, VTb, Ob);
  k_oproj<<<dim3(64, 4), 512, 0, stream>>>(Ob, wto, bo, out);
}